// Round 18
// baseline (4190.151 us; speedup 1.0000x reference)
//
#include <hip/hip_runtime.h>
#include <hip/hip_bf16.h>

// ZOH linear layer: K[1,8192], dim 2048.
// Y2=(0.91A)^2, ER via bf16x3-split MFMA GEMMs; E elementwise from Y2.
// W=inv(A+1e-3 I) f64 in-place flat blocked GJ (gj64 v6 unpivoted col-major,
// stagefix, 64-tile trailing f64 GEMM) + 1 f64 IR step on the solve vector.
// K[91j+i] = (C*AR^j)·(A^i*Bbar): two balanced serial matvec chains (90 steps) + dots.
// (Round-10/16 configuration: best-known-good at ~4.19 ms. f32-inversion variant
// refuted in r17: eps32*kappa*growth ~ 1.2 > 1 -> IR non-convergent.)

#define DIMN 2048
#define MSTEPS 8192
#define RSPLIT 91
#define NSTEPS 90
#define NN ((size_t)DIMN * DIMN)
#define NBLK 32
#define ALD 40   // LDS pitch (bf16) for gemm3 tiles
#define GJP 65   // gj64 panel pitch (f64), odd -> bank-friendly

typedef short short8 __attribute__((ext_vector_type(8)));
typedef float f32x4 __attribute__((ext_vector_type(4)));

__device__ inline void split1(float x, unsigned short& h, unsigned short& l)
{
  __hip_bfloat16 b = __float2bfloat16(x);
  h = *reinterpret_cast<unsigned short*>(&b);
  float r = x - __bfloat162float(b);
  __hip_bfloat16 b2 = __float2bfloat16(r);
  l = *reinterpret_cast<unsigned short*>(&b2);
}

// ---------------- elementwise f32: out = c1*i1+c2*i2 + dval*I ----------------
__global__ __launch_bounds__(256)
void k_combine4(float* out,
                const float* i1, float c1, const float* i2, float c2,
                const float* i3, float c3, const float* i4, float c4,
                float dval)
{
  const int total = DIMN * DIMN;
  for (int idx = blockIdx.x * 256 + threadIdx.x; idx < total; idx += gridDim.x * 256) {
    float v = 0.f;
    if (i1) v = fmaf(c1, i1[idx], v);
    if (i2) v = fmaf(c2, i2[idx], v);
    if (i3) v = fmaf(c3, i3[idx], v);
    if (i4) v = fmaf(c4, i4[idx], v);
    if ((idx >> 11) == (idx & 2047)) v += dval;
    out[idx] = v;
  }
}

// ---------------- M64 = (double)A + 1e-3 I ----------------
__global__ __launch_bounds__(256)
void k_fill64(const float* __restrict__ A, double* __restrict__ M)
{
  const int total = DIMN * DIMN;
  for (int idx = blockIdx.x * 256 + threadIdx.x; idx < total; idx += gridDim.x * 256) {
    double v = (double)A[idx];
    if ((idx >> 11) == (idx & 2047)) v += 1e-3;
    M[idx] = v;
  }
}

// ---------------- split f32 -> bf16 hi/lo (linear) ----------------
__global__ __launch_bounds__(256)
void k_split(const float* __restrict__ in, unsigned short* __restrict__ hi,
             unsigned short* __restrict__ lo)
{
  const int i4 = blockIdx.x * 256 + threadIdx.x;   // grid 4096: NN/4 float4s
  const float4 v = ((const float4*)in)[i4];
  ushort4 h, l;
  split1(v.x, h.x, l.x); split1(v.y, h.y, l.y);
  split1(v.z, h.z, l.z); split1(v.w, h.w, l.w);
  ((ushort4*)hi)[i4] = h;
  ((ushort4*)lo)[i4] = l;
}

// ---------------- split f32 -> bf16 hi/lo, transposed output [n][k] ----------------
__global__ __launch_bounds__(256)
void k_splitT(const float* __restrict__ in, unsigned short* __restrict__ hi,
              unsigned short* __restrict__ lo)
{
  __shared__ float t[32][33];
  const int bx = blockIdx.x * 32, by = blockIdx.y * 32;
  const int lx = threadIdx.x, ly = threadIdx.y; // (32,8)
  for (int dy = 0; dy < 32; dy += 8)
    t[ly + dy][lx] = in[(size_t)(by + ly + dy) * DIMN + bx + lx];
  __syncthreads();
  for (int dy = 0; dy < 32; dy += 8) {
    const size_t o = (size_t)(bx + ly + dy) * DIMN + by + lx;
    unsigned short h, l;
    split1(t[lx][ly + dy], h, l);
    hi[o] = h; lo[o] = l;
  }
}

// ---------------- bf16x3 MFMA GEMM: C = alpha*(A*B) + c1*E1 + c2*E2 ----------------
__global__ __launch_bounds__(256)
void k_gemm3(const unsigned short* __restrict__ Ahg, const unsigned short* __restrict__ Alg,
             const unsigned short* __restrict__ Bhg, const unsigned short* __restrict__ Blg,
             float* __restrict__ C, float alpha,
             const float* E1, float c1, const float* E2, float c2)
{
  __shared__ unsigned short sAh[128 * ALD];
  __shared__ unsigned short sAl[128 * ALD];
  __shared__ unsigned short sBh[128 * ALD];
  __shared__ unsigned short sBl[128 * ALD];
  const int tid = threadIdx.x;
  const int wid = tid >> 6, lane = tid & 63;
  const int lr = lane & 15, lg = lane >> 4;
  const int wm = wid >> 1, wn = wid & 1;
  const int brow = blockIdx.y * 128, bcol = blockIdx.x * 128;
  const int sr = tid >> 1, sh = (tid & 1) * 16;

  const unsigned short* gAh = Ahg + (size_t)(brow + sr) * DIMN + sh;
  const unsigned short* gAl = Alg + (size_t)(brow + sr) * DIMN + sh;
  const unsigned short* gBh = Bhg + (size_t)(bcol + sr) * DIMN + sh;
  const unsigned short* gBl = Blg + (size_t)(bcol + sr) * DIMN + sh;

  f32x4 acc[4][4];
#pragma unroll
  for (int mf = 0; mf < 4; ++mf)
#pragma unroll
    for (int nf = 0; nf < 4; ++nf) acc[mf][nf] = (f32x4){0.f, 0.f, 0.f, 0.f};

  uint4 pa0 = *(const uint4*)gAh;      uint4 pa1 = *(const uint4*)(gAh + 8);
  uint4 pb0 = *(const uint4*)gAl;      uint4 pb1 = *(const uint4*)(gAl + 8);
  uint4 pc0 = *(const uint4*)gBh;      uint4 pc1 = *(const uint4*)(gBh + 8);
  uint4 pd0 = *(const uint4*)gBl;      uint4 pd1 = *(const uint4*)(gBl + 8);

  const int nk = DIMN / 32;
  for (int kt = 0; kt < nk; ++kt) {
    *(uint4*)&sAh[sr * ALD + sh] = pa0;  *(uint4*)&sAh[sr * ALD + sh + 8] = pa1;
    *(uint4*)&sAl[sr * ALD + sh] = pb0;  *(uint4*)&sAl[sr * ALD + sh + 8] = pb1;
    *(uint4*)&sBh[sr * ALD + sh] = pc0;  *(uint4*)&sBh[sr * ALD + sh + 8] = pc1;
    *(uint4*)&sBl[sr * ALD + sh] = pd0;  *(uint4*)&sBl[sr * ALD + sh + 8] = pd1;
    __syncthreads();
    if (kt + 1 < nk) {
      const int o = (kt + 1) * 32;
      pa0 = *(const uint4*)(gAh + o);  pa1 = *(const uint4*)(gAh + o + 8);
      pb0 = *(const uint4*)(gAl + o);  pb1 = *(const uint4*)(gAl + o + 8);
      pc0 = *(const uint4*)(gBh + o);  pc1 = *(const uint4*)(gBh + o + 8);
      pd0 = *(const uint4*)(gBl + o);  pd1 = *(const uint4*)(gBl + o + 8);
    }
#pragma unroll
    for (int mf = 0; mf < 4; ++mf) {
      const int ar = 64 * wm + 16 * mf + lr;
      const short8 ah = *(const short8*)&sAh[ar * ALD + lg * 8];
      const short8 al = *(const short8*)&sAl[ar * ALD + lg * 8];
#pragma unroll
      for (int nf = 0; nf < 4; ++nf) {
        const int br = 64 * wn + 16 * nf + lr;
        const short8 bh = *(const short8*)&sBh[br * ALD + lg * 8];
        const short8 bl = *(const short8*)&sBl[br * ALD + lg * 8];
        acc[mf][nf] = __builtin_amdgcn_mfma_f32_16x16x32_bf16(ah, bh, acc[mf][nf], 0, 0, 0);
        acc[mf][nf] = __builtin_amdgcn_mfma_f32_16x16x32_bf16(ah, bl, acc[mf][nf], 0, 0, 0);
        acc[mf][nf] = __builtin_amdgcn_mfma_f32_16x16x32_bf16(al, bh, acc[mf][nf], 0, 0, 0);
      }
    }
    __syncthreads();
  }
#pragma unroll
  for (int mf = 0; mf < 4; ++mf) {
#pragma unroll
    for (int nf = 0; nf < 4; ++nf) {
      const int col = bcol + 64 * wn + 16 * nf + lr;
#pragma unroll
      for (int i = 0; i < 4; ++i) {
        const int row = brow + 64 * wm + 16 * mf + 4 * lg + i;
        float v = alpha * acc[mf][nf][i];
        if (E1) v = fmaf(c1, E1[(size_t)row * DIMN + col], v);
        if (E2) v = fmaf(c2, E2[(size_t)row * DIMN + col], v);
        C[(size_t)row * DIMN + col] = v;
      }
    }
  }
}

// ---------------- f64 GEMM (VALU): C = alpha*A*B + c1*E1 (64x64 tile) ----------------
#define DBM 64
#define DBK 8
__global__ __launch_bounds__(256)
void k_dgemm(const double* __restrict__ A, int lda,
             const double* __restrict__ B, int ldb,
             double* C, int ldc, int K, double alpha,
             const double* E1, int ld1, double c1)
{
  __shared__ double As[DBK][DBM];
  __shared__ double Bs[DBK][DBM];
  const int tid = threadIdx.x;
  const int tx = tid & 15, ty = tid >> 4;
  const int brow = blockIdx.y * DBM, bcol = blockIdx.x * DBM;

  const int arow = tid >> 2, ac0 = (tid & 3) * 2;
  const int brw  = tid >> 5, bc0 = (tid & 31) * 2;

  const double* Aptr = A + (size_t)(brow + arow) * lda + ac0;
  const double* Bptr = B + (size_t)brw * ldb + (bcol + bc0);

  double2 aPre = *(const double2*)Aptr;
  double2 bPre = *(const double2*)Bptr;

  double acc[4][4];
#pragma unroll
  for (int i = 0; i < 4; ++i)
#pragma unroll
    for (int j = 0; j < 4; ++j) acc[i][j] = 0.0;

  const int nk = K / DBK;
  for (int kt = 0; kt < nk; ++kt) {
    As[ac0 + 0][arow] = aPre.x;
    As[ac0 + 1][arow] = aPre.y;
    Bs[brw][bc0 + 0] = bPre.x;
    Bs[brw][bc0 + 1] = bPre.y;
    __syncthreads();
    if (kt + 1 < nk) {
      aPre = *(const double2*)(Aptr + (size_t)(kt + 1) * DBK);
      bPre = *(const double2*)(Bptr + (size_t)(kt + 1) * DBK * ldb);
    }
#pragma unroll
    for (int kk = 0; kk < DBK; ++kk) {
      double a[4], b[4];
#pragma unroll
      for (int i = 0; i < 4; ++i) a[i] = As[kk][ty * 4 + i];
#pragma unroll
      for (int j = 0; j < 4; ++j) b[j] = Bs[kk][tx * 4 + j];
#pragma unroll
      for (int i = 0; i < 4; ++i)
#pragma unroll
        for (int j = 0; j < 4; ++j)
          acc[i][j] = fma(a[i], b[j], acc[i][j]);
    }
    __syncthreads();
  }
#pragma unroll
  for (int i = 0; i < 4; ++i) {
    const int gi = brow + ty * 4 + i;
#pragma unroll
    for (int j = 0; j < 4; ++j) {
      const int gj = bcol + tx * 4 + j;
      double v = alpha * acc[i][j];
      if (E1) v = fma(c1, E1[(size_t)gi * ld1 + gj], v);
      C[(size_t)gi * ldc + gj] = v;
    }
  }
}

// ---------------- gj64 v6: UNPIVOTED 64x64 f64 GJ, col-major LDS panel ----------------
__global__ __launch_bounds__(256)
void k_gj64(const double* __restrict__ M, int ldm, double* __restrict__ W, int ldw)
{
  __shared__ double a[128][GJP];   // a[c][r] = P[r][c]; [A | I] col-major
  const int tid = threadIdx.x;
  const int rg = tid & 7;          // rows [8rg, 8rg+8)
  const int cg = tid >> 3;         // 0..31

  for (int idx = tid; idx < 64 * 64; idx += 256) {
    const int r = idx >> 6, c = idx & 63;
    a[c][r] = M[(size_t)r * ldm + c];
    a[64 + c][r] = (r == c) ? 1.0 : 0.0;
  }
  __syncthreads();

  for (int p = 0; p < 64; ++p) {
    const double rpv = 1.0 / a[p][p];
    const int c0 = p + 1 + cg;
    const int c1 = c0 + 32;
    const double prs0 = a[c0][p] * rpv;
    const double prs1 = a[c1][p] * rpv;
    double colp[8];
#pragma unroll
    for (int k = 0; k < 4; ++k) {
      const double2 t2 = *(const double2*)&a[p][rg * 8 + 2 * k];
      colp[2 * k] = t2.x; colp[2 * k + 1] = t2.y;
    }
    __syncthreads();
#pragma unroll
    for (int k = 0; k < 8; ++k) {
      const int r = rg * 8 + k;
      const bool isp = (r == p);
      const double v0 = a[c0][r];
      const double v1 = a[c1][r];
      a[c0][r] = isp ? prs0 : fma(-colp[k], prs0, v0);
      a[c1][r] = isp ? prs1 : fma(-colp[k], prs1, v1);
    }
    __syncthreads();
  }

  for (int idx = tid; idx < 64 * 64; idx += 256) {
    const int r = idx >> 6, c = idx & 63;
    W[(size_t)r * ldw + c] = a[64 + c][r];
  }
}

// ---------------- stagefix: blocks 0-31 rowscale; blocks 32-543 colprep ----------------
__global__ __launch_bounds__(256)
void k_stagefix(const double* __restrict__ Dinv, double* __restrict__ M,
                double* __restrict__ Rpan, double* __restrict__ Cpan, int p)
{
  const int blk = blockIdx.x;
  const int tid = threadIdx.x;
  if (blk >= 32) {
    const int idx = (blk - 32) * 256 + tid;   // 2048*64 total
    const int i = idx >> 6, k = idx & 63;
    const bool inP = (i >> 6) == p;
    const size_t mo = (size_t)i * DIMN + p * 64 + k;
    double v = 0.0;
    if (!inP) { v = M[mo]; M[mo] = 0.0; }
    Cpan[idx] = v;
    return;
  }
  __shared__ double As[DBK][DBM];
  __shared__ double Bs[DBK][DBM];
  const double* Mrow = M + (size_t)p * 64 * DIMN;
  const int tx = tid & 15, ty = tid >> 4;
  const int bcol = blk * DBM;

  const int arow = tid >> 2, ac0 = (tid & 3) * 2;
  const int brw  = tid >> 5, bc0 = (tid & 31) * 2;

  const double* Aptr = Dinv + (size_t)arow * 64 + ac0;
  const double* Bptr = Mrow + (size_t)brw * DIMN + (bcol + bc0);

  double2 aPre = *(const double2*)Aptr;
  double2 bPre = *(const double2*)Bptr;

  double acc[4][4];
#pragma unroll
  for (int i = 0; i < 4; ++i)
#pragma unroll
    for (int j = 0; j < 4; ++j) acc[i][j] = 0.0;

  for (int kt = 0; kt < 8; ++kt) {
    As[ac0 + 0][arow] = aPre.x;
    As[ac0 + 1][arow] = aPre.y;
    Bs[brw][bc0 + 0] = bPre.x;
    Bs[brw][bc0 + 1] = bPre.y;
    __syncthreads();
    if (kt + 1 < 8) {
      aPre = *(const double2*)(Aptr + (size_t)(kt + 1) * DBK);
      bPre = *(const double2*)(Bptr + (size_t)(kt + 1) * DBK * DIMN);
    }
#pragma unroll
    for (int kk = 0; kk < DBK; ++kk) {
      double a[4], b[4];
#pragma unroll
      for (int i = 0; i < 4; ++i) a[i] = As[kk][ty * 4 + i];
#pragma unroll
      for (int j = 0; j < 4; ++j) b[j] = Bs[kk][tx * 4 + j];
#pragma unroll
      for (int i = 0; i < 4; ++i)
#pragma unroll
        for (int j = 0; j < 4; ++j)
          acc[i][j] = fma(a[i], b[j], acc[i][j]);
    }
    __syncthreads();
  }
  const bool pivcol = (bcol >> 6) == p;
#pragma unroll
  for (int i = 0; i < 4; ++i) {
    const int gi = ty * 4 + i;
#pragma unroll
    for (int j = 0; j < 4; ++j) {
      const int gj = bcol + tx * 4 + j;
      double v = pivcol ? Dinv[(size_t)gi * 64 + (gj & 63)] : acc[i][j];
      Rpan[(size_t)gi * DIMN + gj] = v;
      M[(size_t)(p * 64 + gi) * DIMN + gj] = v;
    }
  }
}

// ---------------- matvec f32 matrix, f64 vectors ----------------
__global__ __launch_bounds__(256)
void k_mv(const float* __restrict__ Mat, const double* __restrict__ vin,
          double* vout, const double* vadd, double alpha)
{
  const int lane = threadIdx.x & 63;
  const int row = blockIdx.x * 4 + (threadIdx.x >> 6);
  const float* mrow = Mat + (size_t)row * DIMN;
  double acc = 0.0;
  for (int p = 0; p < DIMN; p += 256) {
    const float4 m = *(const float4*)&mrow[p + lane * 4];
    const double* vp = &vin[p + lane * 4];
    acc += (double)m.x * vp[0] + (double)m.y * vp[1] + (double)m.z * vp[2] + (double)m.w * vp[3];
  }
  for (int off = 32; off; off >>= 1) acc += __shfl_down(acc, off);
  if (lane == 0) vout[row] = alpha * acc + (vadd ? vadd[row] : 0.0);
}

// ---------------- matvec f64 matrix ----------------
__global__ __launch_bounds__(256)
void k_mv64(const double* __restrict__ W, const double* __restrict__ vin,
            double* vout, const double* vadd, double alpha)
{
  const int lane = threadIdx.x & 63;
  const int row = blockIdx.x * 4 + (threadIdx.x >> 6);
  const double* mrow = W + (size_t)row * DIMN;
  double acc = 0.0;
  for (int p = 0; p < DIMN; p += 256) {
    const int idx = p + lane * 4;
    const double2 m0 = *(const double2*)&mrow[idx];
    const double2 m1 = *(const double2*)&mrow[idx + 2];
    acc += m0.x * vin[idx] + m0.y * vin[idx + 1] + m1.x * vin[idx + 2] + m1.y * vin[idx + 3];
  }
  for (int off = 32; off; off >>= 1) acc += __shfl_down(acc, off);
  if (lane == 0) vout[row] = alpha * acc + (vadd ? vadd[row] : 0.0);
}

// ---------------- residual: r = y - (A*x + 1e-3*x) ----------------
__global__ __launch_bounds__(256)
void k_mvres(const float* __restrict__ A, const double* __restrict__ x,
             const double* __restrict__ y, double* r)
{
  const int lane = threadIdx.x & 63;
  const int row = blockIdx.x * 4 + (threadIdx.x >> 6);
  const float* mrow = A + (size_t)row * DIMN;
  double acc = 0.0;
  for (int p = 0; p < DIMN; p += 256) {
    const float4 m = *(const float4*)&mrow[p + lane * 4];
    const double* vp = &x[p + lane * 4];
    acc += (double)m.x * vp[0] + (double)m.y * vp[1] + (double)m.z * vp[2] + (double)m.w * vp[3];
  }
  for (int off = 32; off; off >>= 1) acc += __shfl_down(acc, off);
  if (lane == 0) r[row] = y[row] - acc - 1e-3 * x[row];
}

// ---------------- transpose 2048x2048 f32 ----------------
__global__ __launch_bounds__(256)
void k_transpose(const float* __restrict__ in, float* __restrict__ out)
{
  __shared__ float t[32][33];
  const int bx = blockIdx.x * 32, by = blockIdx.y * 32;
  const int lx = threadIdx.x, ly = threadIdx.y;
  for (int dy = 0; dy < 32; dy += 8)
    t[ly + dy][lx] = in[(size_t)(by + ly + dy) * DIMN + bx + lx];
  __syncthreads();
  for (int dy = 0; dy < 32; dy += 8)
    out[(size_t)(bx + ly + dy) * DIMN + by + lx] = t[lx][ly + dy];
}

// ---------------- chain step: vout=(I+E)vin (b<512); uout=(I+ERT)uin (b>=512) ----------------
__global__ __launch_bounds__(256)
void k_chain(const float* __restrict__ E, const float* __restrict__ vin, float* __restrict__ vout,
             const float* __restrict__ ERT, const float* __restrict__ uin, float* __restrict__ uout)
{
  const int lane = threadIdx.x & 63;
  const int w = threadIdx.x >> 6;
  const int b = blockIdx.x;
  const float* mrow; const float* xin; float* xout; int row;
  if (b < 512) { row = b * 4 + w; mrow = E + (size_t)row * DIMN; xin = vin; xout = vout; }
  else { row = (b - 512) * 4 + w; mrow = ERT + (size_t)row * DIMN; xin = uin; xout = uout; }
  float acc = 0.f;
  for (int p = 0; p < DIMN; p += 256) {
    const float4 m = *(const float4*)&mrow[p + lane * 4];
    const float* vp = &xin[p + lane * 4];
    acc = fmaf(m.x, vp[0], acc);
    acc = fmaf(m.y, vp[1], acc);
    acc = fmaf(m.z, vp[2], acc);
    acc = fmaf(m.w, vp[3], acc);
  }
  for (int off = 32; off; off >>= 1) acc += __shfl_down(acc, off);
  if (lane == 0) xout[row] = xin[row] + acc;
}

// ---------------- terms: out[8191-t] = dot(U[t/91], V[t%91]) ----------------
__global__ __launch_bounds__(256)
void k_terms(const float* __restrict__ U, const float* __restrict__ V, float* __restrict__ out)
{
  const int lane = threadIdx.x & 63;
  const int t = blockIdx.x * 4 + (threadIdx.x >> 6);
  const int j = t / RSPLIT, i = t - j * RSPLIT;
  const float* u = U + (size_t)j * DIMN;
  const float* v = V + (size_t)i * DIMN;
  float acc = 0.f;
  for (int p = 0; p < DIMN; p += 256) {
    const float4 a4 = *(const float4*)&u[p + lane * 4];
    const float4 b4 = *(const float4*)&v[p + lane * 4];
    acc = fmaf(a4.x, b4.x, acc); acc = fmaf(a4.y, b4.y, acc);
    acc = fmaf(a4.z, b4.z, acc); acc = fmaf(a4.w, b4.w, acc);
  }
  for (int off = 32; off; off >>= 1) acc += __shfl_down(acc, off);
  if (lane == 0) out[MSTEPS - 1 - t] = acc;
}

// ---------------- small vector inits ----------------
__global__ void k_vecinit(const float* __restrict__ B, double* __restrict__ b64,
                          const float* __restrict__ Cv, float* __restrict__ U0)
{
  const int i = blockIdx.x * 256 + threadIdx.x;
  if (i < DIMN) { b64[i] = 0.01 * (double)B[i]; U0[i] = Cv[i]; }
}
__global__ void k_v0(const double* __restrict__ x64, float* __restrict__ V0)
{
  const int i = blockIdx.x * 256 + threadIdx.x;
  if (i < DIMN) V0[i] = (float)x64[i];
}

extern "C" void kernel_launch(void* const* d_in, const int* in_sizes, int n_in,
                              void* d_out, int out_size, void* d_ws, size_t ws_size,
                              hipStream_t stream)
{
  const float* dA = (const float*)d_in[0];
  const float* dB = (const float*)d_in[1];
  const float* dC = (const float*)d_in[2];
  float* out = (float*)d_out;

  float* fb = (float*)d_ws;
  float* Ebuf = fb;                 // phase0: Ath/Atl (bf16); then E (f32, persistent)
  float* t1 = fb + NN;              // M64 lo / W lo; then Y2h/Y2l (bf16)
  float* t2 = t1 + NN;              // M64 hi / W hi; then Hth/Htl (bf16)
  float* t3 = t2 + NN;              // Y2 (f32) -> ER (f32, in-place epilogue)
  float* t4 = t3 + NN;              // Ah/Al (bf16); then H (f32); then ERT (f32)
  double* M64 = (double*)t1;        // spans t1,t2
  double* scr64 = (double*)(fb + 5 * NN);
  double* Dinv = scr64;                        // 64x64
  double* Cpan = Dinv + 64 * 64;               // 2048x64
  double* Rpan = Cpan + (size_t)DIMN * 64;     // 64x2048
  double* y64 = Rpan + (size_t)DIMN * 64;
  double* x64 = y64 + DIMN;
  double* r64 = x64 + DIMN;
  double* b64 = r64 + DIMN;
  float* V  = (float*)(b64 + DIMN);            // 91 x 2048
  float* Uc = V + (size_t)RSPLIT * DIMN;       // 91 x 2048

  const size_t needed = 5 * NN * 4
                        + (64 * 64 + 2 * (size_t)DIMN * 64 + 4 * (size_t)DIMN) * 8
                        + (size_t)(2 * RSPLIT) * DIMN * 4;
  if (ws_size < needed) return;

  const float* NUL = nullptr;
  dim3 cb(256), cg(2048);

  unsigned short* Ah  = (unsigned short*)t4;   unsigned short* Al  = Ah + NN;
  unsigned short* Ath = (unsigned short*)Ebuf; unsigned short* Atl = Ath + NN;
  unsigned short* Y2h = (unsigned short*)t1;   unsigned short* Y2l = Y2h + NN;
  unsigned short* Hth = (unsigned short*)t2;   unsigned short* Htl = Hth + NN;

  // ---- Phase 0: bf16 splits of A; Y2 = 0.8281*(A*A) via bf16x3 MFMA; E elementwise ----
  k_split<<<dim3(4096), cb, 0, stream>>>(dA, Ah, Al);
  k_splitT<<<dim3(64, 64), dim3(32, 8), 0, stream>>>(dA, Ath, Atl);
  k_gemm3<<<dim3(16, 16), cb, 0, stream>>>(Ah, Al, Ath, Atl, t3, 0.8281f,
                                           NUL, 0.f, NUL, 0.f);                 // Y2
  k_combine4<<<cg, cb, 0, stream>>>(Ebuf, t3, (float)(5e-5 / 0.8281), dA, 0.01f,
                                    NUL, 0, NUL, 0, 0.f);                       // E

  // ---- Phase 1: M64 = A + 1e-3 I; flat blocked GJ inversion in place (f64) ----
  k_fill64<<<cg, cb, 0, stream>>>(dA, M64);
  for (int p = 0; p < NBLK; ++p) {
    double* Mrow = M64 + (size_t)p * 64 * DIMN;
    k_gj64<<<dim3(1), cb, 0, stream>>>(Mrow + p * 64, DIMN, Dinv, 64);
    k_stagefix<<<dim3(544), cb, 0, stream>>>(Dinv, M64, Rpan, Cpan, p);
    k_dgemm<<<dim3(32, 32), cb, 0, stream>>>(Cpan, 64, Rpan, DIMN, M64, DIMN, 64, -1.0,
                                             M64, DIMN, 1.0);
  }

  // ---- Phase 3: Bbar: y = E*(0.01B); x = W*y; 1x f64 IR ----
  k_vecinit<<<dim3(8), cb, 0, stream>>>(dB, b64, dC, Uc);
  k_mv<<<dim3(512), cb, 0, stream>>>(Ebuf, b64, y64, (const double*)nullptr, 1.0);
  k_mv64<<<dim3(512), cb, 0, stream>>>(M64, y64, x64, (const double*)nullptr, 1.0);
  k_mvres<<<dim3(512), cb, 0, stream>>>(dA, x64, y64, r64);
  k_mv64<<<dim3(512), cb, 0, stream>>>(M64, r64, x64, x64, 1.0);
  k_v0<<<dim3(8), cb, 0, stream>>>(x64, V);                                     // V[0] = Bbar

  // ---- Phase 4: ER = Y2*H + Y2/2 + 0.91A (deg-4 PS), H = (0.91/6)A + Y2/24 ----
  k_combine4<<<cg, cb, 0, stream>>>(t4, dA, 0.91f / 6.f, t3, 1.f / 24.f,
                                    NUL, 0, NUL, 0, 0.f);                       // H -> t4
  k_split<<<dim3(4096), cb, 0, stream>>>(t3, Y2h, Y2l);
  k_splitT<<<dim3(64, 64), dim3(32, 8), 0, stream>>>(t4, Hth, Htl);
  k_gemm3<<<dim3(16, 16), cb, 0, stream>>>(Y2h, Y2l, Hth, Htl, t3, 1.f,
                                           t3, 0.5f, dA, 0.91f);                // ER in-place
  k_transpose<<<dim3(64, 64), dim3(32, 8), 0, stream>>>(t3, t4);                // ERT -> t4

  // ---- Phase 5: balanced serial chains (90 steps) + terms ----
  for (int s = 0; s < NSTEPS; ++s) {
    k_chain<<<dim3(1024), cb, 0, stream>>>(Ebuf, V + (size_t)s * DIMN, V + (size_t)(s + 1) * DIMN,
                                           t4, Uc + (size_t)s * DIMN, Uc + (size_t)(s + 1) * DIMN);
  }
  k_terms<<<dim3(2048), cb, 0, stream>>>(Uc, V, out);
}